// Round 9
// baseline (1461.135 us; speedup 1.0000x reference)
//
#include <hip/hip_runtime.h>
#include <math.h>

// Problem constants (match reference)
#define B_   16
#define T_   1024
#define F_   512
#define G_   2
#define V_   320
#define D_   128
#define N_   (B_ * T_)      // 16384 tokens
#define GV   (G_ * V_)      // 640
#define EPS_ 1e-7f

// Kernel config: one block = 32 rows x ONE group (320 cols).
#define ROWS    32
#define THREADS 256         // 4 waves; wave wvx owns rows wvx*8..wvx*8+7
#define KC      16          // k-chunk staged in LDS
#define WSTRIDE 20          // padded LDS row stride (floats)
#define NBLK    (2 * N_ / ROWS)  // 1024 blocks -> 4 blocks/CU, grid fully resident
#define NCHUNK  (F_ / KC)   // 32

// Workspace layout (floats)
#define WS_AVG    0                   // NBLK*V_ = 327680 floats
#define WS_A1     (NBLK * V_)         // hard-argmax ushort[T_*G_*B_] = 16384 floats
#define WS_TICKET (WS_A1 + 16384)     // 1 uint (memset to 0 each launch)

#define FMA4(a, xv, wv_)                                                       \
  a = fmaf(xv.x, wv_.x, a); a = fmaf(xv.y, wv_.y, a);                          \
  a = fmaf(xv.z, wv_.z, a); a = fmaf(xv.w, wv_.w, a);

// Fused: GEMM (x @ w^T + b) + softmax stats + argmaxes + codebook gather +
// last-block stats tail. Group-split blocks: w-slab 25.6 KB -> 4 blocks/CU,
// 4 waves/SIMD (R4-R8 showed the wall is latency exposure at 2 waves/SIMD).
// launch_bounds(256,4) pins VGPR<=128; live set ~117 (acc[5][8]=40) -> no spill.
__global__ __launch_bounds__(THREADS, 4) void k_fused(
    const float* __restrict__ x, const float* __restrict__ w,
    const float* __restrict__ bias, const float* __restrict__ cb,
    const float* __restrict__ gum, float* __restrict__ out,
    float* __restrict__ avg_part, unsigned short* __restrict__ a1buf,
    unsigned int* __restrict__ ticket)
{
  __shared__ float lw[V_][WSTRIDE];    // 25.6 KB  w k-slab (this group), padded
  __shared__ float lx[ROWS][WSTRIDE];  // 2.5 KB   x k-slab, padded
  __shared__ unsigned int sdone;
  const int tid = threadIdx.x;
  const int wvx = tid >> 6;   // wave / row-group 0..3
  const int ln  = tid & 63;
  const int blk = blockIdx.x;
  const int g   = blk & 1;          // group handled by this block
  const int n0  = (blk >> 1) * ROWS;
  const int r0  = wvx * 8;

  float acc[5][8];
#pragma unroll
  for (int j = 0; j < 5; ++j)
#pragma unroll
    for (int r = 0; r < 8; ++r) acc[j][r] = 0.f;

  const float4* w4 = (const float4*)w;
  const float4* x4 = (const float4*)x;
  const int srow = tid >> 2, squad = tid & 3;  // staging map

  for (int c = 0; c < NCHUNK; ++c) {  // 32 chunks
    __syncthreads();
    // stage w k-slab: 320 rows x 16 k (5 float4/thread), x: 32 x 16
#pragma unroll
    for (int it = 0; it < 5; ++it)
      *(float4*)&lw[srow + 64 * it][squad * 4] =
          w4[(size_t)(g * V_ + srow + 64 * it) * (F_ / 4) + c * 4 + squad];
    if (tid < ROWS * 4)
      *(float4*)&lx[srow][squad * 4] =
          x4[(size_t)(n0 + srow) * (F_ / 4) + c * 4 + squad];
    __syncthreads();

#pragma unroll
    for (int kk = 0; kk < 4; ++kk) {
      float4 xreg[8];
#pragma unroll
      for (int r = 0; r < 8; ++r)
        xreg[r] = *(const float4*)&lx[r0 + r][kk * 4];  // wave-uniform broadcast
      float4 wreg[5];                                   // 5 independent ds_reads
#pragma unroll
      for (int j = 0; j < 5; ++j)
        wreg[j] = *(const float4*)&lw[64 * j + ln][kk * 4];
#pragma unroll
      for (int j = 0; j < 5; ++j)
#pragma unroll
        for (int r = 0; r < 8; ++r) { FMA4(acc[j][r], xreg[r], wreg[j]); }
    }
  }

  // ---- phase 2: per-row softmax / argmax / gather, all from registers ----
  float bs[5];
#pragma unroll
  for (int j = 0; j < 5; ++j) bs[j] = bias[g * V_ + 64 * j + ln];

  float racc[5];
#pragma unroll
  for (int j = 0; j < 5; ++j) racc[j] = 0.f;

#pragma unroll
  for (int r = 0; r < 8; ++r) {
    const int n = n0 + r0 + r;
    float L[5], GU[5];
#pragma unroll
    for (int j = 0; j < 5; ++j) {
      L[j]  = acc[j][r] + bs[j];
      GU[j] = gum[(size_t)n * GV + g * V_ + 64 * j + ln];
    }
    // local max/argmax (cols ascend with j -> first-occurrence tie-break)
    float m1 = L[0];         int a1 = ln;
    float m2 = L[0] + GU[0]; int a2 = ln;
#pragma unroll
    for (int j = 1; j < 5; ++j) {
      const int cix = 64 * j + ln;
      if (L[j] > m1) { m1 = L[j]; a1 = cix; }
      const float t2 = L[j] + GU[j];
      if (t2 > m2) { m2 = t2; a2 = cix; }
    }
    // wave reduce (prefer smaller index on exact ties)
    for (int off = 32; off; off >>= 1) {
      float om = __shfl_down(m1, off); int oa = __shfl_down(a1, off);
      if (om > m1 || (om == m1 && oa < a1)) { m1 = om; a1 = oa; }
      float om2 = __shfl_down(m2, off); int oa2 = __shfl_down(a2, off);
      if (om2 > m2 || (om2 == m2 && oa2 < a2)) { m2 = om2; a2 = oa2; }
    }
    m1 = __shfl(m1, 0); a1 = __shfl(a1, 0); a2 = __shfl(a2, 0);

    // softmax (no tau) for avg_probs
    float e[5], s = 0.f;
#pragma unroll
    for (int j = 0; j < 5; ++j) { e[j] = expf(L[j] - m1); s += e[j]; }
    for (int off = 32; off; off >>= 1) s += __shfl_down(s, off);
    s = __shfl(s, 0);
    const float inv = 1.0f / s;
#pragma unroll
    for (int j = 0; j < 5; ++j) racc[j] += e[j] * inv;

    if (ln == 0) {
      const int t = n & (T_ - 1), bidx = n >> 10;
      a1buf[(t * G_ + g) * B_ + bidx] = (unsigned short)a1;
    }
    // quantized[n, g*D : (g+1)*D] = codebook[g, a2, :]
    const float2* cbr = (const float2*)(cb + (size_t)(g * V_ + a2) * D_);
    float2* op = (float2*)(out + (size_t)n * (G_ * D_) + g * D_);
    op[ln] = cbr[ln];
  }

  // ---- block-level avg_probs partial: reduce 4 wave-private copies ----
  __syncthreads();
  float* la = (float*)lw;  // [4][V_] = 5120 floats <= 320*20
#pragma unroll
  for (int j = 0; j < 5; ++j)
    la[wvx * V_ + 64 * j + ln] = racc[j];
  __syncthreads();
  for (int cix = tid; cix < V_; cix += THREADS) {
    float s = 0.f;
#pragma unroll
    for (int v = 0; v < 4; ++v) s += la[v * V_ + cix];
    avg_part[(size_t)blk * V_ + cix] = s;   // blk = 2*tile + g
  }

  // ---- ticket: last block to finish runs the stats tail ----
  __syncthreads();
  if (tid == 0) {
    __threadfence();                       // publish this block's stores
    sdone = atomicAdd(ticket, 1u);         // device-scope
  }
  __syncthreads();
  if (sdone != NBLK - 1) return;
  __threadfence();  // acquire side

  // ===== tail (one block, 256 threads) =====
  float* outs = out + (size_t)N_ * (G_ * D_);

  // (1) code perplexity: per (t,g), histogram of 16 batch argmaxes in regs
  float pplAcc = 0.f;
  for (int item = tid; item < T_ * G_; item += THREADS) {  // 8 iters, coalesced
    const uint4* p = (const uint4*)(a1buf + (size_t)item * B_);
    uint4 u0 = p[0], u1 = p[1];
    int idx[16];
    idx[0]=u0.x&0xffff; idx[1]=u0.x>>16; idx[2]=u0.y&0xffff; idx[3]=u0.y>>16;
    idx[4]=u0.z&0xffff; idx[5]=u0.z>>16; idx[6]=u0.w&0xffff; idx[7]=u0.w>>16;
    idx[8]=u1.x&0xffff; idx[9]=u1.x>>16; idx[10]=u1.y&0xffff; idx[11]=u1.y>>16;
    idx[12]=u1.z&0xffff; idx[13]=u1.z>>16; idx[14]=u1.w&0xffff; idx[15]=u1.w>>16;
    float H = 0.f;
#pragma unroll
    for (int b = 0; b < 16; ++b) {
      int cnt = 0;
#pragma unroll
      for (int b2 = 0; b2 < 16; ++b2) cnt += (idx[b] == idx[b2]) ? 1 : 0;
      H += logf((float)cnt * (1.0f / B_) + EPS_);
    }
    pplAcc += expf(-H * (1.0f / B_));
  }
  float* lxf = (float*)lx;   // 256-float scratch
  lxf[tid] = pplAcc;

  // (2) avg_probs column reduce + p*log(p+eps)
  // avg_part[(2*tile+g)*320 + v] == avg_part[tile*640 + cix], cix = g*320+v
  float* sh = (float*)lw;    // 640-float scratch
  for (int cix = tid; cix < GV; cix += THREADS) {
    float s = 0.f;
    for (int tile = 0; tile < NBLK / 2; ++tile)
      s += avg_part[(size_t)tile * GV + cix];
    const float pv = s * (1.0f / N_);
    sh[cix] = pv * logf(pv + EPS_);
  }
  __syncthreads();

  if (tid < 64) {
    float s0 = 0.f, s1 = 0.f, sc = 0.f;
    for (int j = tid; j < V_; j += 64) { s0 += sh[j]; s1 += sh[V_ + j]; }
#pragma unroll
    for (int v = 0; v < 4; ++v) sc += lxf[tid + 64 * v];
    for (int off = 32; off; off >>= 1) {
      s0 += __shfl_down(s0, off);
      s1 += __shfl_down(s1, off);
      sc += __shfl_down(sc, off);
    }
    if (tid == 0) {
      outs[0] = sc;                          // code_perplexity
      outs[1] = expf(-s0) + expf(-s1);       // prob_perplexity
    }
  }
}

extern "C" void kernel_launch(void* const* d_in, const int* in_sizes, int n_in,
                              void* d_out, int out_size, void* d_ws, size_t ws_size,
                              hipStream_t stream) {
  const float* x   = (const float*)d_in[0];  // (B,T,F)
  const float* w   = (const float*)d_in[1];  // (G*V, F)
  const float* b   = (const float*)d_in[2];  // (G*V,)
  const float* cb  = (const float*)d_in[3];  // (1, G*V, D)
  const float* gum = (const float*)d_in[4];  // (B*T, G, V)
  float* out = (float*)d_out;                // quantized (N*G*D) ++ [code_ppl, prob_ppl]
  float* ws  = (float*)d_ws;

  float* avgp = ws + WS_AVG;
  unsigned short* a1buf = (unsigned short*)(ws + WS_A1);
  unsigned int* ticket  = (unsigned int*)(ws + WS_TICKET);

  hipMemsetAsync(ticket, 0, sizeof(unsigned int), stream);
  k_fused<<<NBLK, THREADS, 0, stream>>>(x, w, b, cb, gum, out, avgp, a1buf, ticket);
}

// Round 10
// 445.381 us; speedup vs baseline: 3.2806x; 3.2806x over previous
//
#include <hip/hip_runtime.h>
#include <math.h>

// Problem constants (match reference)
#define B_   16
#define T_   1024
#define F_   512
#define G_   2
#define V_   320
#define D_   128
#define N_   (B_ * T_)      // 16384 tokens
#define GV   (G_ * V_)      // 640
#define EPS_ 1e-7f

// Kernel config: one block = 32 rows x ONE group (320 cols).
#define ROWS    32
#define THREADS 256         // 4 waves; wave wvx owns rows wvx*8..wvx*8+7
#define KC      16          // k-chunk of w staged in LDS
#define WSTRIDE 20          // padded LDS row stride (floats)
#define NBLK    (2 * N_ / ROWS)  // 1024 blocks
#define NCHUNK  (F_ / KC)   // 32

// Workspace layout (floats)
#define WS_AVG    0                   // NBLK*V_ = 327680 floats
#define WS_A1     (NBLK * V_)         // hard-argmax ushort[T_*G_*B_] = 16384 floats
#define WS_TICKET (WS_A1 + 16384)     // 1 uint (memset to 0 each launch)

#define FMA4(a, xv, wv_)                                                       \
  a = fmaf(xv.x, wv_.x, a); a = fmaf(xv.y, wv_.y, a);                          \
  a = fmaf(xv.z, wv_.z, a); a = fmaf(xv.w, wv_.w, a);

// Fused: GEMM (x @ w^T + b) + softmax stats + argmaxes + codebook gather +
// last-block stats tail.
// Key structure (R5-R9 lessons):
//  - plain __launch_bounds__(256): every allocator-steering attribute either
//    was ignored (waves_per_eu, num_vgpr) or over-applied (min-waves -> VGPR 64,
//    3.5 GB spill traffic in R9). Live set ~70 VGPR fits the default 128.
//  - x rows are WAVE-UNIFORM: readfirstlane'd row index -> compiler emits
//    scalar s_load_dwordx4 (SMEM pipe, SGPR data, fmaf reads SGPR operand
//    directly). x never touches the LDS pipe -> only 5 ds_read_b128 per
//    float4-of-k remain vs 40 FMA4 -> VALU-bound at last.
//  - w k-slab (one group, 320x16, 25.7 KB padded LDS) -> 4-5 blocks/CU.
__global__ __launch_bounds__(THREADS) void k_fused(
    const float* __restrict__ x, const float* __restrict__ w,
    const float* __restrict__ bias, const float* __restrict__ cb,
    const float* __restrict__ gum, float* __restrict__ out,
    float* __restrict__ avg_part, unsigned short* __restrict__ a1buf,
    unsigned int* __restrict__ ticket)
{
  __shared__ float lw[V_][WSTRIDE];    // 25.6 KB  w k-slab (this group), padded
  __shared__ unsigned int sdone;
  const int tid = threadIdx.x;
  const int wvx = tid >> 6;   // wave / row-group 0..3
  const int ln  = tid & 63;
  const int blk = blockIdx.x;
  const int g   = blk & 1;          // group handled by this block
  const int n0  = (blk >> 1) * ROWS;
  const int r0  = wvx * 8;
  // wave-uniform copy of r0 for scalar x addressing
  const int r0u = __builtin_amdgcn_readfirstlane(r0);

  float acc[5][8];
#pragma unroll
  for (int j = 0; j < 5; ++j)
#pragma unroll
    for (int r = 0; r < 8; ++r) acc[j][r] = 0.f;

  const float4* w4 = (const float4*)w;
  const float4* x4 = (const float4*)x;
  const int srow = tid >> 2, squad = tid & 3;  // staging map

  for (int c = 0; c < NCHUNK; ++c) {  // 32 chunks of 16 k
    __syncthreads();
    // stage w k-slab: 320 rows x 16 k (5 float4/thread)
#pragma unroll
    for (int it = 0; it < 5; ++it)
      *(float4*)&lw[srow + 64 * it][squad * 4] =
          w4[(size_t)(g * V_ + srow + 64 * it) * (F_ / 4) + c * 4 + squad];
    __syncthreads();

#pragma unroll
    for (int kk = 0; kk < 4; ++kk) {
      // x: 8 wave-uniform rows -> scalar loads (SMEM), bypasses LDS pipe
      float4 xr_[8];
#pragma unroll
      for (int r = 0; r < 8; ++r)
        xr_[r] = x4[(size_t)(n0 + r0u + r) * (F_ / 4) + c * 4 + kk];
      float4 wreg[5];  // 5 independent ds_read_b128
#pragma unroll
      for (int j = 0; j < 5; ++j)
        wreg[j] = *(const float4*)&lw[64 * j + ln][kk * 4];
#pragma unroll
      for (int j = 0; j < 5; ++j)
#pragma unroll
        for (int r = 0; r < 8; ++r) { FMA4(acc[j][r], xr_[r], wreg[j]); }
    }
  }

  // ---- phase 2: per-row softmax / argmax / gather, all from registers ----
  float bs[5];
#pragma unroll
  for (int j = 0; j < 5; ++j) bs[j] = bias[g * V_ + 64 * j + ln];

  float racc[5];
#pragma unroll
  for (int j = 0; j < 5; ++j) racc[j] = 0.f;

#pragma unroll
  for (int r = 0; r < 8; ++r) {
    const int n = n0 + r0 + r;
    float L[5], GU[5];
#pragma unroll
    for (int j = 0; j < 5; ++j) {
      L[j]  = acc[j][r] + bs[j];
      GU[j] = gum[(size_t)n * GV + g * V_ + 64 * j + ln];
    }
    // local max/argmax (cols ascend with j -> first-occurrence tie-break)
    float m1 = L[0];         int a1 = ln;
    float m2 = L[0] + GU[0]; int a2 = ln;
#pragma unroll
    for (int j = 1; j < 5; ++j) {
      const int cix = 64 * j + ln;
      if (L[j] > m1) { m1 = L[j]; a1 = cix; }
      const float t2 = L[j] + GU[j];
      if (t2 > m2) { m2 = t2; a2 = cix; }
    }
    // wave reduce (prefer smaller index on exact ties)
    for (int off = 32; off; off >>= 1) {
      float om = __shfl_down(m1, off); int oa = __shfl_down(a1, off);
      if (om > m1 || (om == m1 && oa < a1)) { m1 = om; a1 = oa; }
      float om2 = __shfl_down(m2, off); int oa2 = __shfl_down(a2, off);
      if (om2 > m2 || (om2 == m2 && oa2 < a2)) { m2 = om2; a2 = oa2; }
    }
    m1 = __shfl(m1, 0); a1 = __shfl(a1, 0); a2 = __shfl(a2, 0);

    // softmax (no tau) for avg_probs
    float e[5], s = 0.f;
#pragma unroll
    for (int j = 0; j < 5; ++j) { e[j] = expf(L[j] - m1); s += e[j]; }
    for (int off = 32; off; off >>= 1) s += __shfl_down(s, off);
    s = __shfl(s, 0);
    const float inv = 1.0f / s;
#pragma unroll
    for (int j = 0; j < 5; ++j) racc[j] += e[j] * inv;

    if (ln == 0) {
      const int t = n & (T_ - 1), bidx = n >> 10;
      a1buf[(t * G_ + g) * B_ + bidx] = (unsigned short)a1;
    }
    // quantized[n, g*D : (g+1)*D] = codebook[g, a2, :]
    const float2* cbr = (const float2*)(cb + (size_t)(g * V_ + a2) * D_);
    float2* op = (float2*)(out + (size_t)n * (G_ * D_) + g * D_);
    op[ln] = cbr[ln];
  }

  // ---- block-level avg_probs partial: reduce 4 wave-private copies ----
  __syncthreads();
  float* la = (float*)lw;  // [4][V_] = 5120 floats <= 320*20
#pragma unroll
  for (int j = 0; j < 5; ++j)
    la[wvx * V_ + 64 * j + ln] = racc[j];
  __syncthreads();
  for (int cix = tid; cix < V_; cix += THREADS) {
    float s = 0.f;
#pragma unroll
    for (int v = 0; v < 4; ++v) s += la[v * V_ + cix];
    avg_part[(size_t)blk * V_ + cix] = s;   // blk = 2*tile + g
  }

  // ---- ticket: last block to finish runs the stats tail ----
  __syncthreads();
  if (tid == 0) {
    __threadfence();                       // publish this block's stores
    sdone = atomicAdd(ticket, 1u);         // device-scope
  }
  __syncthreads();
  if (sdone != NBLK - 1) return;
  __threadfence();  // acquire side

  // ===== tail (one block, 256 threads) =====
  float* outs = out + (size_t)N_ * (G_ * D_);

  // (1) code perplexity: per (t,g), histogram of 16 batch argmaxes in regs
  float pplAcc = 0.f;
  for (int item = tid; item < T_ * G_; item += THREADS) {  // 8 iters, coalesced
    const uint4* p = (const uint4*)(a1buf + (size_t)item * B_);
    uint4 u0 = p[0], u1 = p[1];
    int idx[16];
    idx[0]=u0.x&0xffff; idx[1]=u0.x>>16; idx[2]=u0.y&0xffff; idx[3]=u0.y>>16;
    idx[4]=u0.z&0xffff; idx[5]=u0.z>>16; idx[6]=u0.w&0xffff; idx[7]=u0.w>>16;
    idx[8]=u1.x&0xffff; idx[9]=u1.x>>16; idx[10]=u1.y&0xffff; idx[11]=u1.y>>16;
    idx[12]=u1.z&0xffff; idx[13]=u1.z>>16; idx[14]=u1.w&0xffff; idx[15]=u1.w>>16;
    float H = 0.f;
#pragma unroll
    for (int b = 0; b < 16; ++b) {
      int cnt = 0;
#pragma unroll
      for (int b2 = 0; b2 < 16; ++b2) cnt += (idx[b] == idx[b2]) ? 1 : 0;
      H += logf((float)cnt * (1.0f / B_) + EPS_);
    }
    pplAcc += expf(-H * (1.0f / B_));
  }
  __shared__ float lppl[THREADS];
  lppl[tid] = pplAcc;

  // (2) avg_probs column reduce + p*log(p+eps)
  // avg_part[(2*tile+g)*320 + v] == avg_part[tile*640 + cix], cix = g*320+v
  float* sh = (float*)lw;    // 640-float scratch
  for (int cix = tid; cix < GV; cix += THREADS) {
    float s = 0.f;
#pragma unroll 4
    for (int tile = 0; tile < NBLK / 2; ++tile)
      s += avg_part[(size_t)tile * GV + cix];
    const float pv = s * (1.0f / N_);
    sh[cix] = pv * logf(pv + EPS_);
  }
  __syncthreads();

  if (tid < 64) {
    float s0 = 0.f, s1 = 0.f, sc = 0.f;
    for (int j = tid; j < V_; j += 64) { s0 += sh[j]; s1 += sh[V_ + j]; }
#pragma unroll
    for (int v = 0; v < 4; ++v) sc += lppl[tid + 64 * v];
    for (int off = 32; off; off >>= 1) {
      s0 += __shfl_down(s0, off);
      s1 += __shfl_down(s1, off);
      sc += __shfl_down(sc, off);
    }
    if (tid == 0) {
      outs[0] = sc;                          // code_perplexity
      outs[1] = expf(-s0) + expf(-s1);       // prob_perplexity
    }
  }
}

extern "C" void kernel_launch(void* const* d_in, const int* in_sizes, int n_in,
                              void* d_out, int out_size, void* d_ws, size_t ws_size,
                              hipStream_t stream) {
  const float* x   = (const float*)d_in[0];  // (B,T,F)
  const float* w   = (const float*)d_in[1];  // (G*V, F)
  const float* b   = (const float*)d_in[2];  // (G*V,)
  const float* cb  = (const float*)d_in[3];  // (1, G*V, D)
  const float* gum = (const float*)d_in[4];  // (B*T, G, V)
  float* out = (float*)d_out;                // quantized (N*G*D) ++ [code_ppl, prob_ppl]
  float* ws  = (float*)d_ws;

  float* avgp = ws + WS_AVG;
  unsigned short* a1buf = (unsigned short*)(ws + WS_A1);
  unsigned int* ticket  = (unsigned int*)(ws + WS_TICKET);

  hipMemsetAsync(ticket, 0, sizeof(unsigned int), stream);
  k_fused<<<NBLK, THREADS, 0, stream>>>(x, w, b, cb, gum, out, avgp, a1buf, ticket);
}